// Round 7
// baseline (612.585 us; speedup 1.0000x reference)
//
#include <hip/hip_runtime.h>

#define D 128

typedef __attribute__((ext_vector_type(8))) short bf16x8;          // 8 bf16 (4 VGPRs)
typedef __attribute__((ext_vector_type(4))) float f32x4;           // MFMA accum / NT loads
typedef __attribute__((ext_vector_type(4))) unsigned short u16x4;  // 4 bf16

__device__ inline unsigned short f2bf(float f) {
    union { float f; unsigned u; } v; v.f = f;
    unsigned r = v.u + 0x7FFF + ((v.u >> 16) & 1);   // RNE
    return (unsigned short)(r >> 16);
}
__device__ inline float bf2f(unsigned short h) {
    union { unsigned u; float f; } v; v.u = ((unsigned)h) << 16; return v.f;
}

// ---------------- casts ----------------

__global__ __launch_bounds__(256) void castx_kernel(const float* __restrict__ x,
                                                    unsigned short* __restrict__ xb, int n4) {
    int i = blockIdx.x * 256 + threadIdx.x;
    if (i < n4) {
        float4 v = reinterpret_cast<const float4*>(x)[i];
        ushort4 r;
        r.x = f2bf(v.x); r.y = f2bf(v.y); r.z = f2bf(v.z); r.w = f2bf(v.w);
        reinterpret_cast<ushort4*>(xb)[i] = r;
    }
}

// Wt[c][k] bf16, k in [0,256): k<128 -> Wl[k][c], k>=128 -> Wr[k-128][c]
__global__ __launch_bounds__(256) void wcast_kernel(const float* __restrict__ W1l,
                                                    const float* __restrict__ W1r,
                                                    const float* __restrict__ W2l,
                                                    const float* __restrict__ W2r,
                                                    unsigned short* __restrict__ Wt1,
                                                    unsigned short* __restrict__ Wt2) {
    int c = blockIdx.x, k = threadIdx.x;
    float v1 = (k < 128) ? W1l[k * 128 + c] : W1r[(k - 128) * 128 + c];
    float v2 = (k < 128) ? W2l[k * 128 + c] : W2r[(k - 128) * 128 + c];
    Wt1[c * 256 + k] = f2bf(v1);
    Wt2[c * 256 + k] = f2bf(v2);
}

// ---------------- CSR build ----------------

__global__ __launch_bounds__(256) void count_kernel(const int* __restrict__ dst,
                                                    int* __restrict__ cnt, int E) {
    int e = blockIdx.x * 256 + threadIdx.x;
    if (e < E) atomicAdd(&cnt[dst[e]], 1);
}

__global__ __launch_bounds__(256) void psum_kernel(const int* __restrict__ cnt,
                                                   int* __restrict__ bsum, int n) {
    __shared__ int wsh[4];
    int b = blockIdx.x, tid = threadIdx.x;
    int i0 = b * 1024 + tid * 4;
    int s = 0;
    #pragma unroll
    for (int j = 0; j < 4; ++j) { int i = i0 + j; if (i < n) s += cnt[i]; }
    #pragma unroll
    for (int d = 1; d < 64; d <<= 1) s += __shfl_xor(s, d, 64);
    if ((tid & 63) == 0) wsh[tid >> 6] = s;
    __syncthreads();
    if (tid == 0) bsum[b] = wsh[0] + wsh[1] + wsh[2] + wsh[3];
}

__global__ __launch_bounds__(64) void bscan_kernel(const int* __restrict__ bsum,
                                                   int* __restrict__ bpre, int nb) {
    int t = threadIdx.x;
    int v = (t < nb) ? bsum[t] : 0;
    int sc = v;
    #pragma unroll
    for (int d = 1; d < 64; d <<= 1) { int u = __shfl_up(sc, d, 64); if (t >= d) sc += u; }
    if (t < nb) bpre[t] = sc - v;
}

__global__ __launch_bounds__(256) void fscan_kernel(const int* __restrict__ cnt,
                                                    const int* __restrict__ bpre,
                                                    int* __restrict__ off,
                                                    int* __restrict__ cursor, int n) {
    __shared__ int wsum[4];
    int b = blockIdx.x, tid = threadIdx.x;
    int lane = tid & 63, wv = tid >> 6;
    int i0 = b * 1024 + tid * 4;
    int v[4]; int s = 0;
    #pragma unroll
    for (int j = 0; j < 4; ++j) { int i = i0 + j; v[j] = (i < n) ? cnt[i] : 0; s += v[j]; }
    int sc = s;
    #pragma unroll
    for (int d = 1; d < 64; d <<= 1) { int u = __shfl_up(sc, d, 64); if (lane >= d) sc += u; }
    if (lane == 63) wsum[wv] = sc;
    __syncthreads();
    int wp = 0;
    for (int j = 0; j < wv; ++j) wp += wsum[j];
    int base = bpre[b] + wp + sc - s;   // exclusive prefix of first elem
    #pragma unroll
    for (int j = 0; j < 4; ++j) {
        int i = i0 + j;
        if (i < n) { cursor[i] = base; off[i + 1] = base + v[j]; }
        base += v[j];
    }
    if (b == 0 && tid == 0) off[0] = 0;
}

__global__ __launch_bounds__(256) void fill_kernel(const int* __restrict__ src,
                                                   const int* __restrict__ dst,
                                                   int* __restrict__ cursor,
                                                   int2* __restrict__ pairs, int E) {
    int e = blockIdx.x * 256 + threadIdx.x;
    if (e < E) {
        int d = dst[e];
        int slot = atomicAdd(&cursor[d], 1);
        pairs[slot] = make_int2(src[e], e);
    }
}

// ---------------- mean aggregation: agg = mean_dst relu(feat[src] + ea) ----------------
// 4 waves/block, 1 node/wave, half-wave per edge, 8 edges in flight per wave.
// Wave batch-preloads 64 CSR pairs, broadcasts via shfl. All shfl sites are
// exec-uniform (uniform branch conditions; odd-tail runs all 64 lanes, accum
// guarded to half 0 with no shfl inside the guard).
// WRITE_EAB: layer 1 emits ea as bf16 in CSR order (sequential NT store).
// EA_BF16:  layer 2 reads the bf16 CSR-ordered copy sequentially (no eid shfl).

template <int WRITE_EAB, int EA_BF16>
__global__ __launch_bounds__(256) void aggregate_kernel(const unsigned short* __restrict__ featb,
                                                        const float* __restrict__ ea,
                                                        unsigned short* __restrict__ eab,
                                                        const int* __restrict__ off,
                                                        const long long* __restrict__ pairs,
                                                        unsigned short* __restrict__ aggb,
                                                        int N) {
    int nd = blockIdx.x * 4 + (threadIdx.x >> 6);
    if (nd >= N) return;
    int t = threadIdx.x & 63;
    int half = t >> 5, l32 = t & 31;
    int s = off[nd], e = off[nd + 1];
    float a0 = 0.f, a1 = 0.f, a2 = 0.f, a3 = 0.f;

    for (int b = s; b < e; b += 64) {
        int cnt = min(64, e - b);
        long long prl = (b + t < e) ? __builtin_nontemporal_load(&pairs[b + t]) : 0LL;
        int psrc = (int)prl;           // pairs[].x = src
        int peid = (int)(prl >> 32);   // pairs[].y = edge id

        auto fetch = [&](int idx, f32x4& ev, u16x4& xv) {
            int sidx = __shfl(psrc, idx, 64);
            int q = b + idx;
            if (EA_BF16) {
                u16x4 eb = __builtin_nontemporal_load(
                    reinterpret_cast<const u16x4*>(&eab[(size_t)q * D + l32 * 4]));
                ev[0] = bf2f(eb[0]); ev[1] = bf2f(eb[1]);
                ev[2] = bf2f(eb[2]); ev[3] = bf2f(eb[3]);
            } else {
                int eidx = __shfl(peid, idx, 64);
                ev = __builtin_nontemporal_load(
                    reinterpret_cast<const f32x4*>(&ea[(size_t)eidx * D + l32 * 4]));
                if (WRITE_EAB) {
                    u16x4 wv;
                    wv[0] = f2bf(ev[0]); wv[1] = f2bf(ev[1]);
                    wv[2] = f2bf(ev[2]); wv[3] = f2bf(ev[3]);
                    __builtin_nontemporal_store(wv,
                        reinterpret_cast<u16x4*>(&eab[(size_t)q * D + l32 * 4]));
                }
            }
            xv = *reinterpret_cast<const u16x4*>(&featb[(size_t)sidx * D + l32 * 4]);
        };
        auto accum = [&](const f32x4& ev, const u16x4& xv) {
            a0 += fmaxf(bf2f(xv[0]) + ev[0], 0.f);
            a1 += fmaxf(bf2f(xv[1]) + ev[1], 0.f);
            a2 += fmaxf(bf2f(xv[2]) + ev[2], 0.f);
            a3 += fmaxf(bf2f(xv[3]) + ev[3], 0.f);
        };

        int p = 0;
        for (; p + 8 <= cnt; p += 8) {          // uniform condition
            f32x4 e0, e1, e2, e3; u16x4 x0, x1, x2, x3;
            fetch(p + half, e0, x0);
            fetch(p + 2 + half, e1, x1);
            fetch(p + 4 + half, e2, x2);
            fetch(p + 6 + half, e3, x3);
            accum(e0, x0); accum(e1, x1); accum(e2, x2); accum(e3, x3);
        }
        if (p + 4 <= cnt) {                     // uniform
            f32x4 e0, e1; u16x4 x0, x1;
            fetch(p + half, e0, x0);
            fetch(p + 2 + half, e1, x1);
            accum(e0, x0); accum(e1, x1);
            p += 4;
        }
        if (p + 2 <= cnt) {                     // uniform
            f32x4 e0; u16x4 x0;
            fetch(p + half, e0, x0);
            accum(e0, x0);
            p += 2;
        }
        if (p < cnt) {                          // uniform; last odd edge
            f32x4 e0; u16x4 x0;
            fetch(p, e0, x0);                   // all 64 lanes shfl/load
            if (half == 0) accum(e0, x0);       // no shfl inside guard
        }
    }

    a0 += __shfl_xor(a0, 32, 64);
    a1 += __shfl_xor(a1, 32, 64);
    a2 += __shfl_xor(a2, 32, 64);
    a3 += __shfl_xor(a3, 32, 64);
    int deg = e - s;
    float inv = 1.f / (float)(deg > 0 ? deg : 1);
    if (half == 0) {
        ushort4 r;
        r.x = f2bf(a0 * inv); r.y = f2bf(a1 * inv);
        r.z = f2bf(a2 * inv); r.w = f2bf(a3 * inv);
        *reinterpret_cast<ushort4*>(&aggb[(size_t)nd * D + l32 * 4]) = r;
    }
}

// ---------------- MFMA GEMM: out = act([A1|A2](Nx256) @ Wt^T + bias) ----------------
// 4 waves/block; wave w owns cols [32w,32w+32) as 2 16-col tiles; B-frags persist in
// registers (2 tiles x 8 k-chunks). 32-row M-tiles (2 A-frags reuse B-frags, 4 MFMA/kc).
// A buffers padded to 32-row multiple; stores guarded by row<N.

template <int RELU, int OUT_BF16>
__global__ __launch_bounds__(256) void gemm_mfma_kernel(const unsigned short* __restrict__ A1,
                                                        const unsigned short* __restrict__ A2,
                                                        const unsigned short* __restrict__ Wt,
                                                        const float* __restrict__ bias,
                                                        float* __restrict__ outf,
                                                        unsigned short* __restrict__ outb,
                                                        int MT, int N) {
    int tid = threadIdx.x;
    int w = tid >> 6;
    int l = tid & 63;
    int lr = l & 15;
    int lg = l >> 4;
    int c0 = w * 32;

    bf16x8 bfr[2][8];
    #pragma unroll
    for (int t = 0; t < 2; ++t)
        #pragma unroll
        for (int kc = 0; kc < 8; ++kc)
            bfr[t][kc] = *reinterpret_cast<const bf16x8*>(
                &Wt[(size_t)(c0 + t * 16 + lr) * 256 + kc * 32 + lg * 8]);

    for (int mt = blockIdx.x; mt < MT; mt += gridDim.x) {
        int r0 = mt * 32;
        f32x4 acc[2][2];
        #pragma unroll
        for (int tr = 0; tr < 2; ++tr)
            #pragma unroll
            for (int tc = 0; tc < 2; ++tc) acc[tr][tc] = {0.f, 0.f, 0.f, 0.f};

        #pragma unroll
        for (int kc = 0; kc < 8; ++kc) {
            const unsigned short* Ap = (kc < 4) ? A1 : A2;
            int k = (kc & 3) * 32 + lg * 8;
            bf16x8 af0 = *reinterpret_cast<const bf16x8*>(&Ap[(size_t)(r0 + lr) * D + k]);
            bf16x8 af1 = *reinterpret_cast<const bf16x8*>(&Ap[(size_t)(r0 + 16 + lr) * D + k]);
            acc[0][0] = __builtin_amdgcn_mfma_f32_16x16x32_bf16(af0, bfr[0][kc], acc[0][0], 0, 0, 0);
            acc[1][0] = __builtin_amdgcn_mfma_f32_16x16x32_bf16(af1, bfr[0][kc], acc[1][0], 0, 0, 0);
            acc[0][1] = __builtin_amdgcn_mfma_f32_16x16x32_bf16(af0, bfr[1][kc], acc[0][1], 0, 0, 0);
            acc[1][1] = __builtin_amdgcn_mfma_f32_16x16x32_bf16(af1, bfr[1][kc], acc[1][1], 0, 0, 0);
        }

        #pragma unroll
        for (int tc = 0; tc < 2; ++tc) {
            int col = c0 + tc * 16 + lr;
            float bv = bias[col];
            #pragma unroll
            for (int tr = 0; tr < 2; ++tr) {
                #pragma unroll
                for (int r = 0; r < 4; ++r) {
                    int row = r0 + tr * 16 + lg * 4 + r;
                    if (row < N) {
                        float v = acc[tr][tc][r] + bv;
                        if (RELU) v = fmaxf(v, 0.f);
                        if (OUT_BF16) outb[(size_t)row * D + col] = f2bf(v);
                        else outf[(size_t)row * D + col] = v;
                    }
                }
            }
        }
    }
}

extern "C" void kernel_launch(void* const* d_in, const int* in_sizes, int n_in,
                              void* d_out, int out_size, void* d_ws, size_t ws_size,
                              hipStream_t stream) {
    const float* x   = (const float*)d_in[0];
    const int*   ei  = (const int*)d_in[1];
    const float* ea  = (const float*)d_in[2];
    const float* W1l = (const float*)d_in[3];
    const float* b1l = (const float*)d_in[4];
    const float* W1r = (const float*)d_in[5];
    const float* W2l = (const float*)d_in[6];
    const float* b2l = (const float*)d_in[7];
    const float* W2r = (const float*)d_in[8];
    float* out = (float*)d_out;

    const int N = in_sizes[0] / D;   // 50000
    const int E = in_sizes[1] / 2;   // 1,600,000
    const int NP = (N + 31) & ~31;   // padded rows for 32-row GEMM tiles
    const int* src = ei;
    const int* dst = ei + E;

    char* ws = (char*)d_ws;
    size_t o = 0;
    auto alloc = [&](size_t bytes) -> void* {
        void* p = ws + o;
        o = (o + bytes + 255) & ~(size_t)255;
        return p;
    };
    int*   cnt    = (int*)alloc((size_t)N * 4);
    int*   off    = (int*)alloc((size_t)(N + 1) * 4);
    int*   cursor = (int*)alloc((size_t)N * 4);
    int*   bsum   = (int*)alloc(256 * 4);
    int*   bpre   = (int*)alloc(256 * 4);
    int2*  pairs  = (int2*)alloc((size_t)E * 8);
    unsigned short* eab  = (unsigned short*)alloc((size_t)E * D * 2);  // 409 MB
    unsigned short* xb   = (unsigned short*)alloc((size_t)NP * D * 2);
    unsigned short* z1b  = (unsigned short*)alloc((size_t)NP * D * 2);
    unsigned short* aggb = (unsigned short*)alloc((size_t)NP * D * 2);
    unsigned short* Wt1  = (unsigned short*)alloc(128 * 256 * 2);
    unsigned short* Wt2  = (unsigned short*)alloc(128 * 256 * 2);
    (void)ws_size; (void)n_in; (void)out_size;

    const int MT = (N + 31) / 32;      // 1563
    const int NB = (N + 1023) / 1024;  // 49 scan blocks (<= 64)
    const int AGB = (N + 3) / 4;       // aggregate blocks (4 nodes each)

    // casts (independent of CSR build)
    castx_kernel<<<(N * D / 4 + 255) / 256, 256, 0, stream>>>(x, xb, N * D / 4);
    wcast_kernel<<<128, 256, 0, stream>>>(W1l, W1r, W2l, W2r, Wt1, Wt2);

    // CSR build
    (void)hipMemsetAsync(cnt, 0, (size_t)N * 4, stream);
    count_kernel<<<(E + 255) / 256, 256, 0, stream>>>(dst, cnt, E);
    psum_kernel<<<NB, 256, 0, stream>>>(cnt, bsum, N);
    bscan_kernel<<<1, 64, 0, stream>>>(bsum, bpre, NB);
    fscan_kernel<<<NB, 256, 0, stream>>>(cnt, bpre, off, cursor, N);
    fill_kernel<<<(E + 255) / 256, 256, 0, stream>>>(src, dst, cursor, pairs, E);

    // Layer 1: agg = mean relu(x[src]+ea); emits eab (bf16, CSR order)
    aggregate_kernel<1, 0><<<AGB, 256, 0, stream>>>(xb, ea, eab, off,
                                                    (const long long*)pairs, aggb, N);
    gemm_mfma_kernel<1, 1><<<1024, 256, 0, stream>>>(aggb, xb, Wt1, b1l, nullptr, z1b, MT, N);

    // Layer 2: agg = mean relu(z1[src]+eab); sequential bf16 ea stream
    aggregate_kernel<0, 1><<<AGB, 256, 0, stream>>>(z1b, nullptr, eab, off,
                                                    (const long long*)pairs, aggb, N);
    gemm_mfma_kernel<0, 0><<<1024, 256, 0, stream>>>(aggb, z1b, Wt2, b2l, out, nullptr, MT, N);
}

// Round 8
// 607.087 us; speedup vs baseline: 1.0091x; 1.0091x over previous
//
#include <hip/hip_runtime.h>

#define D 128

typedef __attribute__((ext_vector_type(8))) short bf16x8;          // 8 bf16 (4 VGPRs)
typedef __attribute__((ext_vector_type(4))) float f32x4;           // MFMA accum / NT loads
typedef __attribute__((ext_vector_type(4))) unsigned short u16x4;  // 4 bf16
typedef __attribute__((ext_vector_type(4))) unsigned char u8x4;    // 4 fp8

__device__ inline unsigned short f2bf(float f) {
    union { float f; unsigned u; } v; v.f = f;
    unsigned r = v.u + 0x7FFF + ((v.u >> 16) & 1);   // RNE
    return (unsigned short)(r >> 16);
}
__device__ inline float bf2f(unsigned short h) {
    union { unsigned u; float f; } v; v.u = ((unsigned)h) << 16; return v.f;
}
// fp8 e4m3fn encode (RNE to 3-bit mantissa, flush-to-zero below 2^-6; |f| < 448 assumed)
__device__ inline unsigned char f2fp8(float f) {
    unsigned u = __float_as_uint(f);
    unsigned s = (u >> 31) << 7;
    unsigned r = (u & 0x7fffffffu) + 0x7FFFF + ((u >> 20) & 1);
    int e = (int)(r >> 23) - 127;
    if (e < -6) return (unsigned char)s;
    return (unsigned char)(s | ((unsigned)(e + 7) << 3) | ((r >> 20) & 7));
}
__device__ inline float fp82f(unsigned c) {
    unsigned ef = (c >> 3) & 0xF, m = c & 7, s = c >> 7;
    unsigned nb = (s << 31) | ((ef + 120) << 23) | (m << 20);
    float nv = __uint_as_float(nb);
    float sv = (s ? -0.001953125f : 0.001953125f) * (float)m;  // subnormal: m * 2^-9
    return ef ? nv : sv;
}

// ---------------- prep: castx (x->bf16) U count(dst) U wcast ----------------

__global__ __launch_bounds__(256) void prep_kernel(const float* __restrict__ x,
                                                   unsigned short* __restrict__ xb, int n4,
                                                   const int* __restrict__ dst,
                                                   int* __restrict__ cnt, int E,
                                                   const float* __restrict__ W1l,
                                                   const float* __restrict__ W1r,
                                                   const float* __restrict__ W2l,
                                                   const float* __restrict__ W2r,
                                                   unsigned short* __restrict__ Wt1,
                                                   unsigned short* __restrict__ Wt2,
                                                   int CAST_B, int CNT_B) {
    int b = blockIdx.x, tid = threadIdx.x;
    if (b < CAST_B) {
        int i = b * 256 + tid;
        if (i < n4) {
            float4 v = reinterpret_cast<const float4*>(x)[i];
            ushort4 r;
            r.x = f2bf(v.x); r.y = f2bf(v.y); r.z = f2bf(v.z); r.w = f2bf(v.w);
            reinterpret_cast<ushort4*>(xb)[i] = r;
        }
    } else if (b < CAST_B + CNT_B) {
        int e = (b - CAST_B) * 256 + tid;
        if (e < E) atomicAdd(&cnt[dst[e]], 1);
    } else {
        int c = b - CAST_B - CNT_B;   // 0..127
        int k = tid;                  // 0..255
        float v1 = (k < 128) ? W1l[k * 128 + c] : W1r[(k - 128) * 128 + c];
        float v2 = (k < 128) ? W2l[k * 128 + c] : W2r[(k - 128) * 128 + c];
        Wt1[c * 256 + k] = f2bf(v1);
        Wt2[c * 256 + k] = f2bf(v2);
    }
}

// ---------------- CSR scan ----------------

__global__ __launch_bounds__(256) void psum_kernel(const int* __restrict__ cnt,
                                                   int* __restrict__ bsum, int n) {
    __shared__ int wsh[4];
    int b = blockIdx.x, tid = threadIdx.x;
    int i0 = b * 1024 + tid * 4;
    int s = 0;
    #pragma unroll
    for (int j = 0; j < 4; ++j) { int i = i0 + j; if (i < n) s += cnt[i]; }
    #pragma unroll
    for (int d = 1; d < 64; d <<= 1) s += __shfl_xor(s, d, 64);
    if ((tid & 63) == 0) wsh[tid >> 6] = s;
    __syncthreads();
    if (tid == 0) bsum[b] = wsh[0] + wsh[1] + wsh[2] + wsh[3];
}

__global__ __launch_bounds__(64) void bscan_kernel(const int* __restrict__ bsum,
                                                   int* __restrict__ bpre, int nb) {
    int t = threadIdx.x;
    int v = (t < nb) ? bsum[t] : 0;
    int sc = v;
    #pragma unroll
    for (int d = 1; d < 64; d <<= 1) { int u = __shfl_up(sc, d, 64); if (t >= d) sc += u; }
    if (t < nb) bpre[t] = sc - v;
}

__global__ __launch_bounds__(256) void fscan_kernel(const int* __restrict__ cnt,
                                                    const int* __restrict__ bpre,
                                                    int* __restrict__ off,
                                                    int* __restrict__ cursor, int n) {
    __shared__ int wsum[4];
    int b = blockIdx.x, tid = threadIdx.x;
    int lane = tid & 63, wv = tid >> 6;
    int i0 = b * 1024 + tid * 4;
    int v[4]; int s = 0;
    #pragma unroll
    for (int j = 0; j < 4; ++j) { int i = i0 + j; v[j] = (i < n) ? cnt[i] : 0; s += v[j]; }
    int sc = s;
    #pragma unroll
    for (int d = 1; d < 64; d <<= 1) { int u = __shfl_up(sc, d, 64); if (lane >= d) sc += u; }
    if (lane == 63) wsum[wv] = sc;
    __syncthreads();
    int wp = 0;
    for (int j = 0; j < wv; ++j) wp += wsum[j];
    int base = bpre[b] + wp + sc - s;   // exclusive prefix of first elem
    #pragma unroll
    for (int j = 0; j < 4; ++j) {
        int i = i0 + j;
        if (i < n) { cursor[i] = base; off[i + 1] = base + v[j]; }
        base += v[j];
    }
    if (b == 0 && tid == 0) off[0] = 0;
}

__global__ __launch_bounds__(256) void fill_kernel(const int* __restrict__ src,
                                                   const int* __restrict__ dst,
                                                   int* __restrict__ cursor,
                                                   long long* __restrict__ pairs, int E) {
    int e = blockIdx.x * 256 + threadIdx.x;
    if (e < E) {
        int d = dst[e];
        int slot = atomicAdd(&cursor[d], 1);
        long long v = (long long)(unsigned)src[e] | ((long long)e << 32);
        __builtin_nontemporal_store(v, &pairs[slot]);
    }
}

// ---------------- mean aggregation: agg = mean_dst relu(feat[src] + ea) ----------------
// 4 waves/block, 1 node/wave, half-wave per edge, 8 edges in flight per wave.
// Wave batch-preloads 64 CSR pairs, broadcasts via shfl. All shfl sites are
// exec-uniform; the final odd edge runs all 64 lanes with accum guarded to half 0.
// EA_FP8=0 (layer 1): read ea f32 NT, emit fp8 e4m3 copy in CSR order.
// EA_FP8=1 (layer 2): read the fp8 CSR-ordered copy sequentially (no eid shfl).

template <int EA_FP8>
__global__ __launch_bounds__(256) void aggregate_kernel(const unsigned short* __restrict__ featb,
                                                        const float* __restrict__ ea,
                                                        unsigned char* __restrict__ eaq,
                                                        const int* __restrict__ off,
                                                        const long long* __restrict__ pairs,
                                                        unsigned short* __restrict__ aggb,
                                                        int N) {
    int nd = blockIdx.x * 4 + (threadIdx.x >> 6);
    if (nd >= N) return;
    int t = threadIdx.x & 63;
    int half = t >> 5, l32 = t & 31;
    int s = off[nd], e = off[nd + 1];
    float a0 = 0.f, a1 = 0.f, a2 = 0.f, a3 = 0.f;

    for (int b = s; b < e; b += 64) {
        int cnt = min(64, e - b);
        long long prl = (b + t < e) ? __builtin_nontemporal_load(&pairs[b + t]) : 0LL;
        int psrc = (int)prl;           // pairs[].x = src
        int peid = (int)(prl >> 32);   // pairs[].y = edge id

        auto fetch = [&](int idx, f32x4& ev, u16x4& xv) {
            int sidx = __shfl(psrc, idx, 64);
            int q = b + idx;
            if (EA_FP8) {
                u8x4 eq = __builtin_nontemporal_load(
                    reinterpret_cast<const u8x4*>(&eaq[(size_t)q * D + l32 * 4]));
                ev[0] = fp82f(eq[0]); ev[1] = fp82f(eq[1]);
                ev[2] = fp82f(eq[2]); ev[3] = fp82f(eq[3]);
            } else {
                int eidx = __shfl(peid, idx, 64);
                ev = __builtin_nontemporal_load(
                    reinterpret_cast<const f32x4*>(&ea[(size_t)eidx * D + l32 * 4]));
                u8x4 wq;
                wq[0] = f2fp8(ev[0]); wq[1] = f2fp8(ev[1]);
                wq[2] = f2fp8(ev[2]); wq[3] = f2fp8(ev[3]);
                __builtin_nontemporal_store(wq,
                    reinterpret_cast<u8x4*>(&eaq[(size_t)q * D + l32 * 4]));
            }
            xv = *reinterpret_cast<const u16x4*>(&featb[(size_t)sidx * D + l32 * 4]);
        };
        auto accum = [&](const f32x4& ev, const u16x4& xv) {
            a0 += fmaxf(bf2f(xv[0]) + ev[0], 0.f);
            a1 += fmaxf(bf2f(xv[1]) + ev[1], 0.f);
            a2 += fmaxf(bf2f(xv[2]) + ev[2], 0.f);
            a3 += fmaxf(bf2f(xv[3]) + ev[3], 0.f);
        };

        int p = 0;
        for (; p + 8 <= cnt; p += 8) {          // uniform condition
            f32x4 e0, e1, e2, e3; u16x4 x0, x1, x2, x3;
            fetch(p + half, e0, x0);
            fetch(p + 2 + half, e1, x1);
            fetch(p + 4 + half, e2, x2);
            fetch(p + 6 + half, e3, x3);
            accum(e0, x0); accum(e1, x1); accum(e2, x2); accum(e3, x3);
        }
        if (p + 4 <= cnt) {                     // uniform
            f32x4 e0, e1; u16x4 x0, x1;
            fetch(p + half, e0, x0);
            fetch(p + 2 + half, e1, x1);
            accum(e0, x0); accum(e1, x1);
            p += 4;
        }
        if (p + 2 <= cnt) {                     // uniform
            f32x4 e0; u16x4 x0;
            fetch(p + half, e0, x0);
            accum(e0, x0);
            p += 2;
        }
        if (p < cnt) {                          // uniform; last odd edge
            f32x4 e0; u16x4 x0;
            fetch(p, e0, x0);                   // all 64 lanes shfl/load
            if (half == 0) accum(e0, x0);       // no shfl inside guard
        }
    }

    a0 += __shfl_xor(a0, 32, 64);
    a1 += __shfl_xor(a1, 32, 64);
    a2 += __shfl_xor(a2, 32, 64);
    a3 += __shfl_xor(a3, 32, 64);
    int deg = e - s;
    float inv = 1.f / (float)(deg > 0 ? deg : 1);
    if (half == 0) {
        ushort4 r;
        r.x = f2bf(a0 * inv); r.y = f2bf(a1 * inv);
        r.z = f2bf(a2 * inv); r.w = f2bf(a3 * inv);
        *reinterpret_cast<ushort4*>(&aggb[(size_t)nd * D + l32 * 4]) = r;
    }
}

// ---------------- MFMA GEMM: out = act([A1|A2](Nx256) @ Wt^T + bias) ----------------
// 4 waves/block; wave w owns cols [32w,32w+32) as 2 16-col tiles; B-frags persist in
// registers (2 tiles x 8 k-chunks). 32-row M-tiles; stores guarded by row<N.

template <int RELU, int OUT_BF16>
__global__ __launch_bounds__(256) void gemm_mfma_kernel(const unsigned short* __restrict__ A1,
                                                        const unsigned short* __restrict__ A2,
                                                        const unsigned short* __restrict__ Wt,
                                                        const float* __restrict__ bias,
                                                        float* __restrict__ outf,
                                                        unsigned short* __restrict__ outb,
                                                        int MT, int N) {
    int tid = threadIdx.x;
    int w = tid >> 6;
    int l = tid & 63;
    int lr = l & 15;
    int lg = l >> 4;
    int c0 = w * 32;

    bf16x8 bfr[2][8];
    #pragma unroll
    for (int t = 0; t < 2; ++t)
        #pragma unroll
        for (int kc = 0; kc < 8; ++kc)
            bfr[t][kc] = *reinterpret_cast<const bf16x8*>(
                &Wt[(size_t)(c0 + t * 16 + lr) * 256 + kc * 32 + lg * 8]);

    for (int mt = blockIdx.x; mt < MT; mt += gridDim.x) {
        int r0 = mt * 32;
        f32x4 acc[2][2];
        #pragma unroll
        for (int tr = 0; tr < 2; ++tr)
            #pragma unroll
            for (int tc = 0; tc < 2; ++tc) acc[tr][tc] = {0.f, 0.f, 0.f, 0.f};

        #pragma unroll
        for (int kc = 0; kc < 8; ++kc) {
            const unsigned short* Ap = (kc < 4) ? A1 : A2;
            int k = (kc & 3) * 32 + lg * 8;
            bf16x8 af0 = *reinterpret_cast<const bf16x8*>(&Ap[(size_t)(r0 + lr) * D + k]);
            bf16x8 af1 = *reinterpret_cast<const bf16x8*>(&Ap[(size_t)(r0 + 16 + lr) * D + k]);
            acc[0][0] = __builtin_amdgcn_mfma_f32_16x16x32_bf16(af0, bfr[0][kc], acc[0][0], 0, 0, 0);
            acc[1][0] = __builtin_amdgcn_mfma_f32_16x16x32_bf16(af1, bfr[0][kc], acc[1][0], 0, 0, 0);
            acc[0][1] = __builtin_amdgcn_mfma_f32_16x16x32_bf16(af0, bfr[1][kc], acc[0][1], 0, 0, 0);
            acc[1][1] = __builtin_amdgcn_mfma_f32_16x16x32_bf16(af1, bfr[1][kc], acc[1][1], 0, 0, 0);
        }

        #pragma unroll
        for (int tc = 0; tc < 2; ++tc) {
            int col = c0 + tc * 16 + lr;
            float bv = bias[col];
            #pragma unroll
            for (int tr = 0; tr < 2; ++tr) {
                #pragma unroll
                for (int r = 0; r < 4; ++r) {
                    int row = r0 + tr * 16 + lg * 4 + r;
                    if (row < N) {
                        float v = acc[tr][tc][r] + bv;
                        if (RELU) v = fmaxf(v, 0.f);
                        if (OUT_BF16) outb[(size_t)row * D + col] = f2bf(v);
                        else outf[(size_t)row * D + col] = v;
                    }
                }
            }
        }
    }
}

extern "C" void kernel_launch(void* const* d_in, const int* in_sizes, int n_in,
                              void* d_out, int out_size, void* d_ws, size_t ws_size,
                              hipStream_t stream) {
    const float* x   = (const float*)d_in[0];
    const int*   ei  = (const int*)d_in[1];
    const float* ea  = (const float*)d_in[2];
    const float* W1l = (const float*)d_in[3];
    const float* b1l = (const float*)d_in[4];
    const float* W1r = (const float*)d_in[5];
    const float* W2l = (const float*)d_in[6];
    const float* b2l = (const float*)d_in[7];
    const float* W2r = (const float*)d_in[8];
    float* out = (float*)d_out;

    const int N = in_sizes[0] / D;   // 50000
    const int E = in_sizes[1] / 2;   // 1,600,000
    const int NP = (N + 31) & ~31;   // padded rows for 32-row GEMM tiles
    const int* src = ei;
    const int* dst = ei + E;

    char* ws = (char*)d_ws;
    size_t o = 0;
    auto alloc = [&](size_t bytes) -> void* {
        void* p = ws + o;
        o = (o + bytes + 255) & ~(size_t)255;
        return p;
    };
    int*   cnt    = (int*)alloc((size_t)N * 4);
    int*   off    = (int*)alloc((size_t)(N + 1) * 4);
    int*   cursor = (int*)alloc((size_t)N * 4);
    int*   bsum   = (int*)alloc(256 * 4);
    int*   bpre   = (int*)alloc(256 * 4);
    long long* pairs = (long long*)alloc((size_t)E * 8);
    unsigned char* eaq = (unsigned char*)alloc((size_t)E * D);   // 205 MB fp8
    unsigned short* xb   = (unsigned short*)alloc((size_t)NP * D * 2);
    unsigned short* z1b  = (unsigned short*)alloc((size_t)NP * D * 2);
    unsigned short* aggb = (unsigned short*)alloc((size_t)NP * D * 2);
    unsigned short* Wt1  = (unsigned short*)alloc(128 * 256 * 2);
    unsigned short* Wt2  = (unsigned short*)alloc(128 * 256 * 2);
    (void)ws_size; (void)n_in; (void)out_size;

    const int MT = (N + 31) / 32;      // 1563
    const int NB = (N + 1023) / 1024;  // 49 scan blocks (<= 64)
    const int AGB = (N + 3) / 4;       // aggregate blocks (4 nodes each)
    const int n4 = N * D / 4;
    const int CAST_B = (n4 + 255) / 256;
    const int CNT_B = (E + 255) / 256;

    // CSR count + casts in one kernel (memset first: count atomics depend on it)
    (void)hipMemsetAsync(cnt, 0, (size_t)N * 4, stream);
    prep_kernel<<<CAST_B + CNT_B + 128, 256, 0, stream>>>(x, xb, n4, dst, cnt, E,
                                                          W1l, W1r, W2l, W2r, Wt1, Wt2,
                                                          CAST_B, CNT_B);
    psum_kernel<<<NB, 256, 0, stream>>>(cnt, bsum, N);
    bscan_kernel<<<1, 64, 0, stream>>>(bsum, bpre, NB);
    fscan_kernel<<<NB, 256, 0, stream>>>(cnt, bpre, off, cursor, N);
    fill_kernel<<<(E + 255) / 256, 256, 0, stream>>>(src, dst, cursor, pairs, E);

    // Layer 1: agg = mean relu(x[src]+ea); emits eaq (fp8 e4m3, CSR order)
    aggregate_kernel<0><<<AGB, 256, 0, stream>>>(xb, ea, eaq, off, pairs, aggb, N);
    gemm_mfma_kernel<1, 1><<<1024, 256, 0, stream>>>(aggb, xb, Wt1, b1l, nullptr, z1b, MT, N);

    // Layer 2: agg = mean relu(z1[src]+eaq); sequential fp8 ea stream
    aggregate_kernel<1><<<AGB, 256, 0, stream>>>(z1b, nullptr, eaq, off, pairs, aggb, N);
    gemm_mfma_kernel<0, 0><<<1024, 256, 0, stream>>>(aggb, z1b, Wt2, b2l, out, nullptr, MT, N);
}